// Round 1
// baseline (29.292 us; speedup 1.0000x reference)
//
#include <hip/hip_runtime.h>

#define ALPHA 0.2f
constexpr int B  = 4;
constexpr int K  = 256;
constexpr int F  = 128;
constexpr int E2 = 256;   // output dim of each of s1/s2
constexpr int ET = 512;   // s1 | s2 concatenated

// ---------------------------------------------------------------------------
// K1: S[b][k][e2] = sum_f x[b,k,f] * Wsel[e2,f]  (+ b_lin for e2>=256)
//     e2 <  256 : Wsel = W[e2, 0:128]           (s1)
//     e2 >= 256 : Wsel = W[e2-256, 128:256]     (s2, + b_lin[e2-256])
// grid (ET/64, K/32, B) = (8,8,4) = 256 blocks, 256 threads
// ---------------------------------------------------------------------------
__global__ __launch_bounds__(256) void k1_gemm(const float* __restrict__ x,
                                               const float* __restrict__ W,
                                               const float* __restrict__ bl,
                                               float* __restrict__ S) {
    __shared__ float xt[32][132];   // +4 pad: lane-varying row reads spread banks
    __shared__ float wt[64][132];
    const int b  = blockIdx.z;
    const int k0 = blockIdx.y * 32;
    const int e0 = blockIdx.x * 64;
    const int tid = threadIdx.x;

    const int col4 = (tid & 31) * 4;
    const int rsub = tid >> 5;               // 0..7
#pragma unroll
    for (int p = 0; p < 4; ++p) {            // 32 rows of x tile
        int row = p * 8 + rsub;
        *(float4*)&xt[row][col4] =
            *(const float4*)&x[(b * K + k0 + row) * F + col4];
    }
#pragma unroll
    for (int p = 0; p < 8; ++p) {            // 64 rows of W tile
        int row = p * 8 + rsub;
        int eg  = e0 + row;
        int wr  = eg & (E2 - 1);             // eg mod 256
        int fb  = (eg >= E2) ? F : 0;
        *(float4*)&wt[row][col4] =
            *(const float4*)&W[wr * (2 * F) + fb + col4];
    }
    __syncthreads();

    const int es = tid & 15;                 // e = e0 + es + 16*t
    const int kb = tid >> 4;                 // k = k0 + kb + 16*kk
    float acc[2][4] = {};
    for (int f4 = 0; f4 < F; f4 += 4) {
        float4 x0 = *(const float4*)&xt[kb][f4];
        float4 x1 = *(const float4*)&xt[kb + 16][f4];
#pragma unroll
        for (int t = 0; t < 4; ++t) {
            float4 wv = *(const float4*)&wt[es + 16 * t][f4];
            acc[0][t] += x0.x * wv.x + x0.y * wv.y + x0.z * wv.z + x0.w * wv.w;
            acc[1][t] += x1.x * wv.x + x1.y * wv.y + x1.z * wv.z + x1.w * wv.w;
        }
    }

    const bool isS2 = (e0 >= E2);            // block-uniform
#pragma unroll
    for (int t = 0; t < 4; ++t) {
        int   eg  = e0 + es + 16 * t;
        float add = isS2 ? bl[eg - E2] : 0.f;
#pragma unroll
        for (int kk = 0; kk < 2; ++kk) {
            int kg = k0 + kb + 16 * kk;
            S[(b * K + kg) * ET + eg] = acc[kk][t] + add;
        }
    }
}

// ---------------------------------------------------------------------------
// K2: E[b][i][j] = sum_e a[e]*leakyrelu(s1[b,i,e] + s2p[b,j,e]) + bias[i,j]
//     leakyrelu(p) = 0.6p + 0.4|p|  (alpha = 0.2)
// grid (K/32, K/16, B) = (8,16,4) = 512 blocks, 256 threads
// wave w handles i = i0 + 4w .. +3; lane = (jl, eh): j = j0+jl, e-half eh
// ---------------------------------------------------------------------------
__global__ __launch_bounds__(256) void k2_score(const float* __restrict__ S,
                                                const float* __restrict__ a,
                                                const float* __restrict__ bias,
                                                float* __restrict__ Eo) {
    __shared__ float s1t[16][260];
    __shared__ float s2t[32][260];
    __shared__ float av6[256];
    __shared__ float av4[256];
    const int b  = blockIdx.z;
    const int i0 = blockIdx.y * 16;
    const int j0 = blockIdx.x * 32;
    const int tid = threadIdx.x;

    { float av = a[tid]; av6[tid] = 0.6f * av; av4[tid] = 0.4f * av; }

    const int col4 = (tid & 63) * 4;         // 0..252 covers e 0..255
    const int rsub = tid >> 6;               // 0..3
#pragma unroll
    for (int p = 0; p < 4; ++p) {            // 16 rows of s1
        int row = p * 4 + rsub;
        *(float4*)&s1t[row][col4] =
            *(const float4*)&S[(b * K + i0 + row) * ET + col4];
    }
#pragma unroll
    for (int p = 0; p < 8; ++p) {            // 32 rows of s2 (+b_lin already)
        int row = p * 4 + rsub;
        *(float4*)&s2t[row][col4] =
            *(const float4*)&S[(b * K + j0 + row) * ET + E2 + col4];
    }
    __syncthreads();

    const int w    = tid >> 6;
    const int lane = tid & 63;
    const int jl   = lane & 31;
    const int eh   = lane >> 5;              // e-half: lanes 0-31 low, 32-63 high
    float acc[4] = {0.f, 0.f, 0.f, 0.f};
    const int ebeg = eh * 128;

#pragma unroll 2
    for (int e = ebeg; e < ebeg + 128; e += 4) {
        float4 sv = *(const float4*)&s2t[jl][e];     // lane-varying (8-phase min)
        float4 c6 = *(const float4*)&av6[e];         // 2-addr broadcast
        float4 c4 = *(const float4*)&av4[e];
#pragma unroll
        for (int is = 0; is < 4; ++is) {
            float4 s1v = *(const float4*)&s1t[w * 4 + is][e];  // broadcast
            float p0 = s1v.x + sv.x;
            float p1 = s1v.y + sv.y;
            float p2 = s1v.z + sv.z;
            float p3 = s1v.w + sv.w;
            acc[is] += c6.x * p0 + c4.x * fabsf(p0);
            acc[is] += c6.y * p1 + c4.y * fabsf(p1);
            acc[is] += c6.z * p2 + c4.z * fabsf(p2);
            acc[is] += c6.w * p3 + c4.w * fabsf(p3);
        }
    }
    // combine the two e-halves (lanes l and l^32 hold partial sums)
#pragma unroll
    for (int is = 0; is < 4; ++is) acc[is] += __shfl_xor(acc[is], 32);

    if (eh == 0) {
        int jg = j0 + jl;
#pragma unroll
        for (int is = 0; is < 4; ++is) {
            int ig = i0 + w * 4 + is;
            Eo[(b * K + ig) * K + jg] = acc[is] + bias[ig * K + jg];
        }
    }
}

// ---------------------------------------------------------------------------
// K3: softmax over j (in-register, per wave) + PV + sigmoid
// grid (K/4, B) = (64,4) = 256 blocks, 256 threads
// wave w: softmax of row i0+w; PV: wave w handles j in [64w,64w+64) for ALL
// 4 rows of the block (each x row read exactly once per block), partial sums
// reduced across waves through LDS.
// ---------------------------------------------------------------------------
__global__ __launch_bounds__(256) void k3_softmax_pv(const float* __restrict__ Ein,
                                                     const float* __restrict__ x,
                                                     float* __restrict__ out) {
    __shared__ float p_lds[K][4];        // [j][i-sub]
    __shared__ float yp[4][4][F];        // [wave][i-sub][f]
    __shared__ float rinv_lds[4];
    const int b   = blockIdx.y;
    const int i0  = blockIdx.x * 4;
    const int tid = threadIdx.x;
    const int w   = tid >> 6;
    const int lane = tid & 63;

    // ---- softmax of row i = i0 + w (unnormalized p; 1/sum applied at end)
    const int i = i0 + w;
    const float* Erow = &Ein[(b * K + i) * K];
    float er[4];
#pragma unroll
    for (int m = 0; m < 4; ++m) er[m] = Erow[m * 64 + lane];
    float mx = fmaxf(fmaxf(er[0], er[1]), fmaxf(er[2], er[3]));
#pragma unroll
    for (int off = 32; off > 0; off >>= 1) mx = fmaxf(mx, __shfl_xor(mx, off));
    float pm[4], s = 0.f;
#pragma unroll
    for (int m = 0; m < 4; ++m) { pm[m] = __expf(er[m] - mx); s += pm[m]; }
#pragma unroll
    for (int off = 32; off > 0; off >>= 1) s += __shfl_xor(s, off);
    if (lane == 0) rinv_lds[w] = 1.f / s;
#pragma unroll
    for (int m = 0; m < 4; ++m) p_lds[m * 64 + lane][w] = pm[m];
    __syncthreads();

    // ---- PV: y[i][f] = sum_j p[i][j] * x[b][j][f]
    float acc[4][2] = {};
    const float* xb = &x[(size_t)(b * K) * F];
#pragma unroll 4
    for (int jj = 0; jj < 64; ++jj) {
        int j = w * 64 + jj;
        float2 xv = *(const float2*)&xb[j * F + lane * 2];
        float4 pj = *(const float4*)&p_lds[j][0];    // broadcast
        acc[0][0] += pj.x * xv.x;  acc[0][1] += pj.x * xv.y;
        acc[1][0] += pj.y * xv.x;  acc[1][1] += pj.y * xv.y;
        acc[2][0] += pj.z * xv.x;  acc[2][1] += pj.z * xv.y;
        acc[3][0] += pj.w * xv.x;  acc[3][1] += pj.w * xv.y;
    }
#pragma unroll
    for (int ii = 0; ii < 4; ++ii) {
        yp[w][ii][lane * 2]     = acc[ii][0];
        yp[w][ii][lane * 2 + 1] = acc[ii][1];
    }
    __syncthreads();

    // ---- cross-wave reduce + sigmoid + store (512 outputs, 2 per thread)
#pragma unroll
    for (int r = 0; r < 2; ++r) {
        int id = r * 256 + tid;
        int ii = id >> 7;                    // 0..3
        int f  = id & 127;
        float y = yp[0][ii][f] + yp[1][ii][f] + yp[2][ii][f] + yp[3][ii][f];
        float z = y * rinv_lds[ii];
        out[(b * K + i0 + ii) * F + f] = 1.f / (1.f + __expf(-z));
    }
}

// ---------------------------------------------------------------------------
extern "C" void kernel_launch(void* const* d_in, const int* in_sizes, int n_in,
                              void* d_out, int out_size, void* d_ws, size_t ws_size,
                              hipStream_t stream) {
    const float* x    = (const float*)d_in[0];   // (4,256,128)
    const float* W    = (const float*)d_in[1];   // (256,256)
    const float* bl   = (const float*)d_in[2];   // (256,)
    const float* a    = (const float*)d_in[3];   // (256,)
    const float* bias = (const float*)d_in[4];   // (256,256)
    float* out = (float*)d_out;                  // (4,256,128)

    float* S = (float*)d_ws;                               // B*K*ET fp32 = 2 MB
    float* E = (float*)((char*)d_ws + (size_t)B * K * ET * sizeof(float)); // 1 MB

    k1_gemm      <<<dim3(ET / 64, K / 32, B), 256, 0, stream>>>(x, W, bl, S);
    k2_score     <<<dim3(K / 32, K / 16, B), 256, 0, stream>>>(S, a, bias, E);
    k3_softmax_pv<<<dim3(K / 4, B),          256, 0, stream>>>(E, x, out);
}